// Round 3
// baseline (2255.641 us; speedup 1.0000x reference)
//
#include <hip/hip_runtime.h>

#define N_NODES 50000
#define N_EDGES 300000
#define G_GRAPHS 1024
#define HID 256
#define NLAYERS 4
#define EPB 64

typedef unsigned short ushort_t;

__device__ __forceinline__ float bf2f(ushort_t u) {
  unsigned int x = ((unsigned int)u) << 16;
  return __builtin_bit_cast(float, x);
}
__device__ __forceinline__ ushort_t f2bf(float f) {
  unsigned int x = __builtin_bit_cast(unsigned int, f);
  unsigned int lsb = (x >> 16) & 1u;
  x += 0x7fffu + lsb;
  return (ushort_t)(x >> 16);
}

// h(bf16) = relu(x @ encW + encB), x: [N,11] f32, encW: [11,256] f32
__global__ __launch_bounds__(256) void k_encoder(const float* __restrict__ x,
    const float* __restrict__ W, const float* __restrict__ b,
    ushort_t* __restrict__ h, int n)
{
  int j = threadIdx.x;
  float wcol[11];
#pragma unroll
  for (int k = 0; k < 11; ++k) wcol[k] = W[k * HID + j];
  float bj = b[j];
  __shared__ float xs[8][11];
  int base = blockIdx.x * 8;
  if (j < 88) {
    int r = j / 11, k = j % 11;
    int row = base + r;
    if (row < n) xs[r][k] = x[row * 11 + k];
  }
  __syncthreads();
#pragma unroll
  for (int r = 0; r < 8; ++r) {
    int row = base + r;
    if (row >= n) break;
    float acc = bj;
#pragma unroll
    for (int k = 0; k < 11; ++k) acc += xs[r][k] * wcol[k];
    h[(size_t)row * HID + j] = f2bf(fmaxf(acc, 0.f));
  }
}

// aggr[dst] += relu(h[src] + edge_attr @ eW + eb) per edge; h bf16, rest f32
__global__ __launch_bounds__(256) void k_scatter(const ushort_t* __restrict__ h,
    const float* __restrict__ ea, const int* __restrict__ src,
    const int* __restrict__ dst, const float* __restrict__ eW,
    const float* __restrict__ eb, float* __restrict__ aggr, int E)
{
  __shared__ float w[5][HID];
  __shared__ float bias[HID];
  __shared__ float eat[EPB][5];
  __shared__ int sidx[EPB], didx[EPB];
  int j = threadIdx.x;
#pragma unroll
  for (int k = 0; k < 5; ++k) w[k][j] = eW[k * HID + j];
  bias[j] = eb[j];
  int base = blockIdx.x * EPB;
  if (j < EPB) {
    int e = base + j;
    if (e < E) { sidx[j] = src[e]; didx[j] = dst[e]; }
  }
  for (int t = j; t < EPB * 5; t += 256) {
    int e = base + t / 5;
    if (e < E) eat[t / 5][t % 5] = ea[(size_t)e * 5 + (t % 5)];
  }
  __syncthreads();
  int cnt = min(EPB, E - base);
  for (int t = 0; t < cnt; ++t) {
    int s = sidx[t], d = didx[t];
    float m = bias[j];
#pragma unroll
    for (int k = 0; k < 5; ++k) m = fmaf(eat[t][k], w[k][j], m);
    m += bf2f(h[(size_t)s * HID + j]);
    m = fmaxf(m, 0.f);
    unsafeAtomicAdd(&aggr[(size_t)d * HID + j], m);
  }
}

// out[M,256] = (bf2f(Abf) (+Aadd)) @ W + bias, optional relu.
// W f32 [256,256] row-major. OUT_BF16 selects output type.
template<int OUT_BF16, int DO_RELU>
__global__ __launch_bounds__(256) void k_gemm(const ushort_t* __restrict__ Abf,
    const float* __restrict__ Aadd, const float* __restrict__ W,
    const float* __restrict__ bias, void* __restrict__ outp, int M)
{
  __shared__ float As[16][68];  // A tile transposed [k][m]
  __shared__ float Ws[16][68];  // W tile [k][n]
  int tid = threadIdx.x;
  int tx = tid & 15, ty = tid >> 4;
  int row0 = blockIdx.x * 64, col0 = blockIdx.y * 64;
  float acc[4][4] = {};
  int lr = tid >> 2, lk = (tid & 3) * 4;       // A staging: row, k-quad
  int wk = tid >> 4, wn = (tid & 15) * 4;      // W staging: k, n-quad
  for (int k0 = 0; k0 < HID; k0 += 16) {
    float4 av = make_float4(0.f, 0.f, 0.f, 0.f);
    int gr = row0 + lr;
    if (gr < M) {
      ushort4 hv = *(const ushort4*)(Abf + (size_t)gr * HID + k0 + lk);
      av = make_float4(bf2f(hv.x), bf2f(hv.y), bf2f(hv.z), bf2f(hv.w));
      if (Aadd) {
        float4 bv = *(const float4*)(Aadd + (size_t)gr * HID + k0 + lk);
        av.x += bv.x; av.y += bv.y; av.z += bv.z; av.w += bv.w;
      }
    }
    As[lk + 0][lr] = av.x; As[lk + 1][lr] = av.y;
    As[lk + 2][lr] = av.z; As[lk + 3][lr] = av.w;
    float4 wf = *(const float4*)(W + (size_t)(k0 + wk) * HID + col0 + wn);
    *(float4*)&Ws[wk][wn] = wf;
    __syncthreads();
#pragma unroll
    for (int i = 0; i < 16; ++i) {
      float4 a = *(const float4*)&As[i][ty * 4];
      float4 bv = *(const float4*)&Ws[i][tx * 4];
      float ar[4] = {a.x, a.y, a.z, a.w};
      float br[4] = {bv.x, bv.y, bv.z, bv.w};
#pragma unroll
      for (int r = 0; r < 4; ++r)
#pragma unroll
        for (int c = 0; c < 4; ++c)
          acc[r][c] = fmaf(ar[r], br[c], acc[r][c]);
    }
    __syncthreads();
  }
  float4 bq = *(const float4*)(bias + col0 + tx * 4);
  float bf[4] = {bq.x, bq.y, bq.z, bq.w};
#pragma unroll
  for (int r = 0; r < 4; ++r) {
    int row = row0 + ty * 4 + r;
    if (row < M) {
      float o[4];
#pragma unroll
      for (int c = 0; c < 4; ++c) {
        o[c] = acc[r][c] + bf[c];
        if (DO_RELU) o[c] = fmaxf(o[c], 0.f);
      }
      if (OUT_BF16) {
        ushort4 ov = make_ushort4(f2bf(o[0]), f2bf(o[1]), f2bf(o[2]), f2bf(o[3]));
        *(ushort4*)((ushort_t*)outp + (size_t)row * HID + col0 + tx * 4) = ov;
      } else {
        float4 ov = make_float4(o[0], o[1], o[2], o[3]);
        *(float4*)((float*)outp + (size_t)row * HID + col0 + tx * 4) = ov;
      }
    }
  }
}

__global__ __launch_bounds__(256) void k_bn_stats(const float* __restrict__ z,
    float* __restrict__ stats, int n)
{
  int j = threadIdx.x;
  float s1 = 0.f, s2 = 0.f;
  for (int r = blockIdx.x; r < n; r += gridDim.x) {
    float v = z[(size_t)r * HID + j];
    s1 += v; s2 = fmaf(v, v, s2);
  }
  unsafeAtomicAdd(&stats[j], s1);
  unsafeAtomicAdd(&stats[HID + j], s2);
}

__global__ void k_bn_finalize(const float* __restrict__ stats,
    const float* __restrict__ g, const float* __restrict__ b,
    float* __restrict__ ss, int n)
{
  int j = threadIdx.x;
  float inv_n = 1.f / (float)n;
  float mu = stats[j] * inv_n;
  float var = stats[HID + j] * inv_n - mu * mu;
  float rs = rsqrtf(var + 1e-5f);
  float sc = g[j] * rs;
  ss[j] = sc;
  ss[HID + j] = b[j] - mu * sc;
}

// h(bf16) = relu(z*scale + shift) + h
__global__ __launch_bounds__(256) void k_bn_apply(const float* __restrict__ z,
    const float* __restrict__ ss, ushort_t* __restrict__ h, int total4)
{
  int idx = blockIdx.x * 256 + threadIdx.x;
  if (idx >= total4) return;
  int col = (idx & 63) * 4;
  float4 zv = *(const float4*)(z + (size_t)idx * 4);
  ushort4 hv = *(const ushort4*)(h + (size_t)idx * 4);
  float o0 = fmaxf(fmaf(zv.x, ss[col + 0], ss[HID + col + 0]), 0.f) + bf2f(hv.x);
  float o1 = fmaxf(fmaf(zv.y, ss[col + 1], ss[HID + col + 1]), 0.f) + bf2f(hv.y);
  float o2 = fmaxf(fmaf(zv.z, ss[col + 2], ss[HID + col + 2]), 0.f) + bf2f(hv.z);
  float o3 = fmaxf(fmaf(zv.w, ss[col + 3], ss[HID + col + 3]), 0.f) + bf2f(hv.w);
  *(ushort4*)(h + (size_t)idx * 4) = make_ushort4(f2bf(o0), f2bf(o1), f2bf(o2), f2bf(o3));
}

__global__ __launch_bounds__(256) void k_pool(const ushort_t* __restrict__ h,
    const int* __restrict__ batch, float* __restrict__ psum,
    float* __restrict__ pmax, float* __restrict__ pcnt, int n)
{
  int i = blockIdx.x;
  int j = threadIdx.x;
  int g = batch[i];
  float v = bf2f(h[(size_t)i * HID + j]);
  unsafeAtomicAdd(&psum[(size_t)g * HID + j], v);
  atomicMax((int*)&pmax[(size_t)g * HID + j], __float_as_int(v));  // h >= 0
  if (j == 0) unsafeAtomicAdd(&pcnt[g], 1.f);
}

__global__ __launch_bounds__(256) void k_head(const float* __restrict__ psum,
    const float* __restrict__ pmax, const float* __restrict__ pcnt,
    const float* __restrict__ W1, const float* __restrict__ b1,
    const float* __restrict__ W2, const float* __restrict__ b2,
    const float* __restrict__ W3, const float* __restrict__ b3,
    float* __restrict__ out)
{
  __shared__ float gf[3 * HID];
  __shared__ float g1[HID];
  __shared__ float red[4];
  int g = blockIdx.x, j = threadIdx.x;
  float cntv = fmaxf(pcnt[g], 1.f);
  float s = psum[(size_t)g * HID + j];
  gf[j] = s / cntv;
  gf[HID + j] = s;
  gf[2 * HID + j] = pmax[(size_t)g * HID + j];
  __syncthreads();
  float acc = b1[j];
  for (int k = 0; k < 3 * HID; ++k) acc = fmaf(gf[k], W1[(size_t)k * HID + j], acc);
  g1[j] = fmaxf(acc, 0.f);
  __syncthreads();
  float p = 0.f;
  if (j < 128) {
    float a2 = b2[j];
    for (int k = 0; k < HID; ++k) a2 = fmaf(g1[k], W2[(size_t)k * 128 + j], a2);
    p = fmaxf(a2, 0.f) * W3[j];
  }
#pragma unroll
  for (int off = 32; off > 0; off >>= 1) p += __shfl_down(p, off);
  if ((j & 63) == 0) red[j >> 6] = p;
  __syncthreads();
  if (j == 0) out[g] = red[0] + red[1] + b3[0];
}

extern "C" void kernel_launch(void* const* d_in, const int* in_sizes, int n_in,
                              void* d_out, int out_size, void* d_ws, size_t ws_size,
                              hipStream_t stream)
{
  const float* x     = (const float*)d_in[0];
  const int*   ei    = (const int*)d_in[1];
  const float* ea    = (const float*)d_in[2];
  const int*   batch = (const int*)d_in[3];
  const float* encW  = (const float*)d_in[4];
  const float* encB  = (const float*)d_in[5];
  const float* edgeW = (const float*)d_in[6];
  const float* edgeB = (const float*)d_in[7];
  const float* W1    = (const float*)d_in[8];
  const float* b1    = (const float*)d_in[9];
  const float* W2    = (const float*)d_in[10];
  const float* b2    = (const float*)d_in[11];
  const float* bng   = (const float*)d_in[12];
  const float* bnb   = (const float*)d_in[13];
  const float* hW1   = (const float*)d_in[14];
  const float* hb1   = (const float*)d_in[15];
  const float* hW2   = (const float*)d_in[16];
  const float* hb2   = (const float*)d_in[17];
  const float* hW3   = (const float*)d_in[18];
  const float* hb3   = (const float*)d_in[19];
  float* out = (float*)d_out;

  const size_t NH = (size_t)N_NODES * HID;
  const size_t GH = (size_t)G_GRAPHS * HID;
  // fp32 region first (16B-aligned), then bf16 region. Total ~104.5 MB.
  float* A     = (float*)d_ws;       // aggr, then z2 [N,HID] f32
  float* stats = A + NH;             // 512
  float* ss    = stats + 512;        // 512
  float* psum  = ss + 512;           // G*HID
  float* pmax  = psum + GH;          // G*HID
  float* pcnt  = pmax + GH;          // G
  ushort_t* h  = (ushort_t*)(pcnt + G_GRAPHS);  // [N,HID] bf16
  ushort_t* z1 = h + NH;                         // [N,HID] bf16

  const int* src = ei;
  const int* dst = ei + N_EDGES;

  k_encoder<<<(N_NODES + 7) / 8, 256, 0, stream>>>(x, encW, encB, h, N_NODES);

  for (int l = 0; l < NLAYERS; ++l) {
    hipMemsetAsync(A, 0, NH * sizeof(float), stream);
    k_scatter<<<(N_EDGES + EPB - 1) / EPB, 256, 0, stream>>>(
        h, ea, src, dst, edgeW + (size_t)l * 5 * HID, edgeB + (size_t)l * HID,
        A, N_EDGES);
    // z1 = relu((h + aggr) @ W1 + b1)   (bf16 out)
    k_gemm<1, 1><<<dim3((N_NODES + 63) / 64, HID / 64), 256, 0, stream>>>(
        h, A, W1 + (size_t)l * HID * HID, b1 + (size_t)l * HID, z1, N_NODES);
    // z2 = z1 @ W2 + b2                 (f32 out, overwrites aggr)
    k_gemm<0, 0><<<dim3((N_NODES + 63) / 64, HID / 64), 256, 0, stream>>>(
        z1, nullptr, W2 + (size_t)l * HID * HID, b2 + (size_t)l * HID, A, N_NODES);
    hipMemsetAsync(stats, 0, 512 * sizeof(float), stream);
    k_bn_stats<<<512, 256, 0, stream>>>(A, stats, N_NODES);
    k_bn_finalize<<<1, 256, 0, stream>>>(stats, bng + (size_t)l * HID,
                                         bnb + (size_t)l * HID, ss, N_NODES);
    k_bn_apply<<<(N_NODES * HID / 4 + 255) / 256, 256, 0, stream>>>(
        A, ss, h, N_NODES * HID / 4);
  }

  hipMemsetAsync(psum, 0, (2 * GH + G_GRAPHS) * sizeof(float), stream);
  k_pool<<<N_NODES, 256, 0, stream>>>(h, batch, psum, pmax, pcnt, N_NODES);
  k_head<<<G_GRAPHS, 256, 0, stream>>>(psum, pmax, pcnt, hW1, hb1, hW2, hb2,
                                       hW3, hb3, out);
}

// Round 4
// 1474.567 us; speedup vs baseline: 1.5297x; 1.5297x over previous
//
#include <hip/hip_runtime.h>

#define N_NODES 50000
#define N_EDGES 300000
#define G_GRAPHS 1024
#define HID 256
#define NLAYERS 4
#define NPB 8  // nodes per gather block (50000/8 = 6250 blocks)

typedef unsigned short ushort_t;

__device__ __forceinline__ float bf2f(ushort_t u) {
  unsigned int x = ((unsigned int)u) << 16;
  return __builtin_bit_cast(float, x);
}
__device__ __forceinline__ ushort_t f2bf(float f) {
  unsigned int x = __builtin_bit_cast(unsigned int, f);
  unsigned int lsb = (x >> 16) & 1u;
  x += 0x7fffu + lsb;
  return (ushort_t)(x >> 16);
}

// h(bf16) = relu(x @ encW + encB)
__global__ __launch_bounds__(256) void k_encoder(const float* __restrict__ x,
    const float* __restrict__ W, const float* __restrict__ b,
    ushort_t* __restrict__ h, int n)
{
  int j = threadIdx.x;
  float wcol[11];
#pragma unroll
  for (int k = 0; k < 11; ++k) wcol[k] = W[k * HID + j];
  float bj = b[j];
  __shared__ float xs[8][11];
  int base = blockIdx.x * 8;
  if (j < 88) {
    int r = j / 11, k = j % 11;
    int row = base + r;
    if (row < n) xs[r][k] = x[row * 11 + k];
  }
  __syncthreads();
#pragma unroll
  for (int r = 0; r < 8; ++r) {
    int row = base + r;
    if (row >= n) break;
    float acc = bj;
#pragma unroll
    for (int k = 0; k < 11; ++k) acc += xs[r][k] * wcol[k];
    h[(size_t)row * HID + j] = f2bf(fmaxf(acc, 0.f));
  }
}

// ---- CSR build: offs starts as zeroed counts; hist -> scan -> fill ----
__global__ __launch_bounds__(256) void k_hist(const int* __restrict__ dst,
    int* __restrict__ offs, int E)
{
  int e = blockIdx.x * 256 + threadIdx.x;
  if (e < E) atomicAdd(&offs[dst[e]], 1);
}

// single-block exclusive scan (wave-scan based), in place: counts -> starts
__global__ __launch_bounds__(1024) void k_scan(int* __restrict__ offs, int n)
{
  __shared__ int wsum[16];
  __shared__ int s_carry;
  int tid = threadIdx.x, lane = tid & 63, wid = tid >> 6;
  if (tid == 0) s_carry = 0;
  __syncthreads();
  for (int base = 0; base < n; base += 1024) {
    int idx = base + tid;
    int v = (idx < n) ? offs[idx] : 0;
    int x = v;
#pragma unroll
    for (int off = 1; off < 64; off <<= 1) {
      int t = __shfl_up(x, off);
      if (lane >= off) x += t;
    }
    if (lane == 63) wsum[wid] = x;
    __syncthreads();
    if (wid == 0 && lane < 16) {
      int w = wsum[lane];
#pragma unroll
      for (int off = 1; off < 16; off <<= 1) {
        int t = __shfl_up(w, off);
        if (lane >= off) w += t;
      }
      wsum[lane] = w;  // inclusive scan of wave sums
    }
    __syncthreads();
    int wbase = (wid == 0) ? 0 : wsum[wid - 1];
    int excl = s_carry + wbase + x - v;
    int total = wsum[15];
    __syncthreads();
    if (idx < n) offs[idx] = excl;
    if (tid == 0) s_carry += total;
    __syncthreads();
  }
  if (tid == 0) offs[n] = s_carry;
}

// epair[p] = (edge id, src). Advances offs[i] from start -> end of segment i.
__global__ __launch_bounds__(256) void k_fill(const int* __restrict__ src,
    const int* __restrict__ dst, int* __restrict__ offs,
    int2* __restrict__ epair, int E)
{
  int e = blockIdx.x * 256 + threadIdx.x;
  if (e < E) {
    int d = dst[e];
    int p = atomicAdd(&offs[d], 1);
    epair[p] = make_int2(e, src[e]);
  }
}

// aggr[i] (bf16) = sum over in-edges of relu(h[src] + ea @ eW + eb)
// post-fill offs[i] = segment end; lo(i) = offs[i-1] (0 for i=0)
__global__ __launch_bounds__(256) void k_gather(const ushort_t* __restrict__ h,
    const float* __restrict__ ea, const int* __restrict__ offs,
    const int2* __restrict__ epair, const float* __restrict__ eW,
    const float* __restrict__ eb, ushort_t* __restrict__ aggr)
{
  __shared__ float w[5][HID];
  __shared__ float bias[HID];
  __shared__ int s_off[NPB + 1];
  int j = threadIdx.x;
#pragma unroll
  for (int k = 0; k < 5; ++k) w[k][j] = eW[k * HID + j];
  bias[j] = eb[j];
  int node0 = blockIdx.x * NPB;
  if (j <= NPB) {
    int node = node0 + j - 1;
    s_off[j] = (node >= 0) ? offs[node] : 0;
  }
  __syncthreads();
#pragma unroll
  for (int t = 0; t < NPB; ++t) {
    int lo = s_off[t], hi = s_off[t + 1];
    float a = 0.f;
    for (int p = lo; p < hi; ++p) {
      int2 pr = epair[p];                       // broadcast, L1-sequential
      const float* eap = ea + (size_t)pr.x * 5; // broadcast
      float m = bias[j];
      m = fmaf(eap[0], w[0][j], m);
      m = fmaf(eap[1], w[1][j], m);
      m = fmaf(eap[2], w[2][j], m);
      m = fmaf(eap[3], w[3][j], m);
      m = fmaf(eap[4], w[4][j], m);
      m += bf2f(h[(size_t)pr.y * HID + j]);
      a += fmaxf(m, 0.f);
    }
    aggr[(size_t)(node0 + t) * HID + j] = f2bf(a);
  }
}

// out(bf16)[M,256] = (bf2f(Abf) (+bf2f(Aadd))) @ W + bias, optional relu.
// STATS: accumulate column sum/sumsq of (pre-rounding f32) output into stats.
template<int DO_RELU, int STATS>
__global__ __launch_bounds__(256) void k_gemm(const ushort_t* __restrict__ Abf,
    const ushort_t* __restrict__ Aadd, const float* __restrict__ W,
    const float* __restrict__ bias, ushort_t* __restrict__ outp,
    float* __restrict__ stats, int M)
{
  __shared__ float As[16][68];  // A tile transposed [k][m]
  __shared__ float Ws[16][68];  // W tile [k][n]
  int tid = threadIdx.x;
  int tx = tid & 15, ty = tid >> 4;
  int row0 = blockIdx.x * 64, col0 = blockIdx.y * 64;
  float acc[4][4] = {};
  int lr = tid >> 2, lk = (tid & 3) * 4;       // A staging: row, k-quad
  int wk = tid >> 4, wn = (tid & 15) * 4;      // W staging: k, n-quad
  for (int k0 = 0; k0 < HID; k0 += 16) {
    float4 av = make_float4(0.f, 0.f, 0.f, 0.f);
    int gr = row0 + lr;
    if (gr < M) {
      ushort4 hv = *(const ushort4*)(Abf + (size_t)gr * HID + k0 + lk);
      av = make_float4(bf2f(hv.x), bf2f(hv.y), bf2f(hv.z), bf2f(hv.w));
      if (Aadd) {
        ushort4 bv = *(const ushort4*)(Aadd + (size_t)gr * HID + k0 + lk);
        av.x += bf2f(bv.x); av.y += bf2f(bv.y);
        av.z += bf2f(bv.z); av.w += bf2f(bv.w);
      }
    }
    As[lk + 0][lr] = av.x; As[lk + 1][lr] = av.y;
    As[lk + 2][lr] = av.z; As[lk + 3][lr] = av.w;
    float4 wf = *(const float4*)(W + (size_t)(k0 + wk) * HID + col0 + wn);
    *(float4*)&Ws[wk][wn] = wf;
    __syncthreads();
#pragma unroll
    for (int i = 0; i < 16; ++i) {
      float4 a = *(const float4*)&As[i][ty * 4];
      float4 bv = *(const float4*)&Ws[i][tx * 4];
      float ar[4] = {a.x, a.y, a.z, a.w};
      float br[4] = {bv.x, bv.y, bv.z, bv.w};
#pragma unroll
      for (int r = 0; r < 4; ++r)
#pragma unroll
        for (int c = 0; c < 4; ++c)
          acc[r][c] = fmaf(ar[r], br[c], acc[r][c]);
    }
    __syncthreads();
  }
  float4 bq = *(const float4*)(bias + col0 + tx * 4);
  float bf[4] = {bq.x, bq.y, bq.z, bq.w};
  float scol[4] = {0.f, 0.f, 0.f, 0.f}, qcol[4] = {0.f, 0.f, 0.f, 0.f};
#pragma unroll
  for (int r = 0; r < 4; ++r) {
    int row = row0 + ty * 4 + r;
    if (row < M) {
      float o[4];
#pragma unroll
      for (int c = 0; c < 4; ++c) {
        o[c] = acc[r][c] + bf[c];
        if (DO_RELU) o[c] = fmaxf(o[c], 0.f);
        if (STATS) { scol[c] += o[c]; qcol[c] = fmaf(o[c], o[c], qcol[c]); }
      }
      ushort4 ov = make_ushort4(f2bf(o[0]), f2bf(o[1]), f2bf(o[2]), f2bf(o[3]));
      *(ushort4*)(outp + (size_t)row * HID + col0 + tx * 4) = ov;
    }
  }
  if (STATS) {
    // reuse As/Ws for column reduction (all threads past final K-loop sync)
#pragma unroll
    for (int c = 0; c < 4; ++c) {
      As[ty][tx * 4 + c] = scol[c];
      Ws[ty][tx * 4 + c] = qcol[c];
    }
    __syncthreads();
    if (tid < 64) {
      float s = 0.f, q = 0.f;
#pragma unroll
      for (int k = 0; k < 16; ++k) { s += As[k][tid]; q += Ws[k][tid]; }
      unsafeAtomicAdd(&stats[col0 + tid], s);
      unsafeAtomicAdd(&stats[HID + col0 + tid], q);
    }
  }
}

__global__ void k_bn_finalize(const float* __restrict__ stats,
    const float* __restrict__ g, const float* __restrict__ b,
    float* __restrict__ ss, int n)
{
  int j = threadIdx.x;
  float inv_n = 1.f / (float)n;
  float mu = stats[j] * inv_n;
  float var = stats[HID + j] * inv_n - mu * mu;
  float rs = rsqrtf(var + 1e-5f);
  float sc = g[j] * rs;
  ss[j] = sc;
  ss[HID + j] = b[j] - mu * sc;
}

// h(bf16) = relu(z*scale + shift) + h ; z is bf16
__global__ __launch_bounds__(256) void k_bn_apply(const ushort_t* __restrict__ z,
    const float* __restrict__ ss, ushort_t* __restrict__ h, int total4)
{
  int idx = blockIdx.x * 256 + threadIdx.x;
  if (idx >= total4) return;
  int col = (idx & 63) * 4;
  ushort4 zv = *(const ushort4*)(z + (size_t)idx * 4);
  ushort4 hv = *(const ushort4*)(h + (size_t)idx * 4);
  float o0 = fmaxf(fmaf(bf2f(zv.x), ss[col + 0], ss[HID + col + 0]), 0.f) + bf2f(hv.x);
  float o1 = fmaxf(fmaf(bf2f(zv.y), ss[col + 1], ss[HID + col + 1]), 0.f) + bf2f(hv.y);
  float o2 = fmaxf(fmaf(bf2f(zv.z), ss[col + 2], ss[HID + col + 2]), 0.f) + bf2f(hv.z);
  float o3 = fmaxf(fmaf(bf2f(zv.w), ss[col + 3], ss[HID + col + 3]), 0.f) + bf2f(hv.w);
  *(ushort4*)(h + (size_t)idx * 4) = make_ushort4(f2bf(o0), f2bf(o1), f2bf(o2), f2bf(o3));
}

__device__ __forceinline__ int lbound(const int* __restrict__ b, int n, int key) {
  int lo = 0, hi = n;
  while (lo < hi) {
    int mid = (lo + hi) >> 1;
    if (b[mid] < key) lo = mid + 1; else hi = mid;
  }
  return lo;
}

// fused pool (batch sorted -> contiguous ranges) + head MLP
__global__ __launch_bounds__(256) void k_head(const ushort_t* __restrict__ h,
    const int* __restrict__ batch,
    const float* __restrict__ W1, const float* __restrict__ b1,
    const float* __restrict__ W2, const float* __restrict__ b2,
    const float* __restrict__ W3, const float* __restrict__ b3,
    float* __restrict__ out)
{
  __shared__ float gf[3 * HID];
  __shared__ float g1[HID];
  __shared__ float red[4];
  int g = blockIdx.x, j = threadIdx.x;
  int lo = lbound(batch, N_NODES, g);
  int hi = lbound(batch, N_NODES, g + 1);
  float s = 0.f, mx = 0.f;  // h >= 0 by construction
  for (int i = lo; i < hi; ++i) {
    float v = bf2f(h[(size_t)i * HID + j]);
    s += v; mx = fmaxf(mx, v);
  }
  float cntv = fmaxf((float)(hi - lo), 1.f);
  gf[j] = s / cntv;
  gf[HID + j] = s;
  gf[2 * HID + j] = mx;
  __syncthreads();
  float acc = b1[j];
  for (int k = 0; k < 3 * HID; ++k) acc = fmaf(gf[k], W1[(size_t)k * HID + j], acc);
  g1[j] = fmaxf(acc, 0.f);
  __syncthreads();
  float p = 0.f;
  if (j < 128) {
    float a2 = b2[j];
    for (int k = 0; k < HID; ++k) a2 = fmaf(g1[k], W2[(size_t)k * 128 + j], a2);
    p = fmaxf(a2, 0.f) * W3[j];
  }
#pragma unroll
  for (int off = 32; off > 0; off >>= 1) p += __shfl_down(p, off);
  if ((j & 63) == 0) red[j >> 6] = p;
  __syncthreads();
  if (j == 0) out[g] = red[0] + red[1] + b3[0];
}

extern "C" void kernel_launch(void* const* d_in, const int* in_sizes, int n_in,
                              void* d_out, int out_size, void* d_ws, size_t ws_size,
                              hipStream_t stream)
{
  const float* x     = (const float*)d_in[0];
  const int*   ei    = (const int*)d_in[1];
  const float* ea    = (const float*)d_in[2];
  const int*   batch = (const int*)d_in[3];
  const float* encW  = (const float*)d_in[4];
  const float* encB  = (const float*)d_in[5];
  const float* edgeW = (const float*)d_in[6];
  const float* edgeB = (const float*)d_in[7];
  const float* W1    = (const float*)d_in[8];
  const float* b1    = (const float*)d_in[9];
  const float* W2    = (const float*)d_in[10];
  const float* b2    = (const float*)d_in[11];
  const float* bng   = (const float*)d_in[12];
  const float* bnb   = (const float*)d_in[13];
  const float* hW1   = (const float*)d_in[14];
  const float* hb1   = (const float*)d_in[15];
  const float* hW2   = (const float*)d_in[16];
  const float* hb2   = (const float*)d_in[17];
  const float* hW3   = (const float*)d_in[18];
  const float* hb3   = (const float*)d_in[19];
  float* out = (float*)d_out;

  const size_t NH = (size_t)N_NODES * HID;
  // layout (~79.4 MB total):
  float* stats  = (float*)d_ws;                  // 512
  float* ss     = stats + 512;                   // 512
  int*   offs   = (int*)(ss + 512);              // 50001 (+1 pad for align)
  int2*  epair  = (int2*)(offs + 50002);         // 300000 int2
  ushort_t* A   = (ushort_t*)(epair + N_EDGES);  // aggr / z2 [N,HID] bf16
  ushort_t* h   = A + NH;                        // [N,HID] bf16
  ushort_t* z1  = h + NH;                        // [N,HID] bf16

  const int* src = ei;
  const int* dst = ei + N_EDGES;

  // CSR build (once per call)
  hipMemsetAsync(offs, 0, 50001 * sizeof(int), stream);
  k_hist<<<(N_EDGES + 255) / 256, 256, 0, stream>>>(dst, offs, N_EDGES);
  k_scan<<<1, 1024, 0, stream>>>(offs, N_NODES);
  k_fill<<<(N_EDGES + 255) / 256, 256, 0, stream>>>(src, dst, offs, epair, N_EDGES);

  k_encoder<<<(N_NODES + 7) / 8, 256, 0, stream>>>(x, encW, encB, h, N_NODES);

  for (int l = 0; l < NLAYERS; ++l) {
    k_gather<<<N_NODES / NPB, 256, 0, stream>>>(
        h, ea, offs, epair, edgeW + (size_t)l * 5 * HID, edgeB + (size_t)l * HID, A);
    hipMemsetAsync(stats, 0, 512 * sizeof(float), stream);
    // z1 = relu((h + aggr) @ W1 + b1)
    k_gemm<1, 0><<<dim3((N_NODES + 63) / 64, HID / 64), 256, 0, stream>>>(
        h, A, W1 + (size_t)l * HID * HID, b1 + (size_t)l * HID, z1, nullptr, N_NODES);
    // z2 = z1 @ W2 + b2, with fused column stats
    k_gemm<0, 1><<<dim3((N_NODES + 63) / 64, HID / 64), 256, 0, stream>>>(
        z1, nullptr, W2 + (size_t)l * HID * HID, b2 + (size_t)l * HID, A, stats, N_NODES);
    k_bn_finalize<<<1, 256, 0, stream>>>(stats, bng + (size_t)l * HID,
                                         bnb + (size_t)l * HID, ss, N_NODES);
    k_bn_apply<<<(N_NODES * HID / 4 + 255) / 256, 256, 0, stream>>>(
        A, ss, h, N_NODES * HID / 4);
  }

  k_head<<<G_GRAPHS, 256, 0, stream>>>(h, batch, hW1, hb1, hW2, hb2, hW3, hb3, out);
}

// Round 5
// 1169.900 us; speedup vs baseline: 1.9281x; 1.2604x over previous
//
#include <hip/hip_runtime.h>

#define N_NODES 50000
#define N_EDGES 300000
#define G_GRAPHS 1024
#define HID 256
#define NLAYERS 4

typedef unsigned short ushort_t;
typedef __attribute__((ext_vector_type(8))) short bf16x8;
typedef __attribute__((ext_vector_type(4))) float f32x4;

__device__ __forceinline__ float bf2f(ushort_t u) {
  unsigned int x = ((unsigned int)u) << 16;
  return __builtin_bit_cast(float, x);
}
__device__ __forceinline__ ushort_t f2bf(float f) {
  unsigned int x = __builtin_bit_cast(unsigned int, f);
  unsigned int lsb = (x >> 16) & 1u;
  x += 0x7fffu + lsb;
  return (ushort_t)(x >> 16);
}

// h(bf16) = relu(x @ encW + encB)
__global__ __launch_bounds__(256) void k_encoder(const float* __restrict__ x,
    const float* __restrict__ W, const float* __restrict__ b,
    ushort_t* __restrict__ h, int n)
{
  int j = threadIdx.x;
  float wcol[11];
#pragma unroll
  for (int k = 0; k < 11; ++k) wcol[k] = W[k * HID + j];
  float bj = b[j];
  __shared__ float xs[8][11];
  int base = blockIdx.x * 8;
  if (j < 88) {
    int r = j / 11, k = j % 11;
    int row = base + r;
    if (row < n) xs[r][k] = x[row * 11 + k];
  }
  __syncthreads();
#pragma unroll
  for (int r = 0; r < 8; ++r) {
    int row = base + r;
    if (row >= n) break;
    float acc = bj;
#pragma unroll
    for (int k = 0; k < 11; ++k) acc += xs[r][k] * wcol[k];
    h[(size_t)row * HID + j] = f2bf(fmaxf(acc, 0.f));
  }
}

// ---- CSR build ----
__global__ __launch_bounds__(256) void k_hist(const int* __restrict__ dst,
    int* __restrict__ offs, int E)
{
  int e = blockIdx.x * 256 + threadIdx.x;
  if (e < E) atomicAdd(&offs[dst[e]], 1);
}

__global__ __launch_bounds__(1024) void k_scan(int* __restrict__ offs, int n)
{
  __shared__ int wsum[16];
  __shared__ int s_carry;
  int tid = threadIdx.x, lane = tid & 63, wid = tid >> 6;
  if (tid == 0) s_carry = 0;
  __syncthreads();
  for (int base = 0; base < n; base += 1024) {
    int idx = base + tid;
    int v = (idx < n) ? offs[idx] : 0;
    int x = v;
#pragma unroll
    for (int off = 1; off < 64; off <<= 1) {
      int t = __shfl_up(x, off);
      if (lane >= off) x += t;
    }
    if (lane == 63) wsum[wid] = x;
    __syncthreads();
    if (wid == 0 && lane < 16) {
      int w = wsum[lane];
#pragma unroll
      for (int off = 1; off < 16; off <<= 1) {
        int t = __shfl_up(w, off);
        if (lane >= off) w += t;
      }
      wsum[lane] = w;
    }
    __syncthreads();
    int wbase = (wid == 0) ? 0 : wsum[wid - 1];
    int excl = s_carry + wbase + x - v;
    int total = wsum[15];
    __syncthreads();
    if (idx < n) offs[idx] = excl;
    if (tid == 0) s_carry += total;
    __syncthreads();
  }
  if (tid == 0) offs[n] = s_carry;
}

__global__ __launch_bounds__(256) void k_fill(const int* __restrict__ src,
    const int* __restrict__ dst, int* __restrict__ offs,
    int2* __restrict__ epair, int E)
{
  int e = blockIdx.x * 256 + threadIdx.x;
  if (e < E) {
    int d = dst[e];
    int p = atomicAdd(&offs[d], 1);
    epair[p] = make_int2(e, src[e]);
  }
}

// W [256][256] f32 -> Wt [n][k] bf16 (transposed), nmats via grid.y
__global__ __launch_bounds__(256) void k_prep(const float* __restrict__ W,
    ushort_t* __restrict__ Wt)
{
  __shared__ float ld[16][257];
  int mat = blockIdx.y;
  int k0 = blockIdx.x * 16;
  const float* Wm = W + (size_t)mat * HID * HID;
  ushort_t* Wtm = Wt + (size_t)mat * HID * HID;
  int tid = threadIdx.x;
#pragma unroll
  for (int i = 0; i < 16; ++i) ld[i][tid] = Wm[(size_t)(k0 + i) * HID + tid];
  __syncthreads();
#pragma unroll
  for (int v = 0; v < 4; ++v) {
    ushort4 u = make_ushort4(f2bf(ld[v*4+0][tid]), f2bf(ld[v*4+1][tid]),
                             f2bf(ld[v*4+2][tid]), f2bf(ld[v*4+3][tid]));
    *(ushort4*)&Wtm[(size_t)tid * HID + k0 + v * 4] = u;
  }
}

// one wave per node: zin[i] = h[i] + sum_in-edges relu(h[src] + ea@eW + eb)
__global__ __launch_bounds__(256) void k_gather(const ushort_t* __restrict__ h,
    const float* __restrict__ ea, const int* __restrict__ offs,
    const int2* __restrict__ epair, const float* __restrict__ eW,
    const float* __restrict__ eb, ushort_t* __restrict__ zin, int n)
{
  int tid = threadIdx.x;
  int wave = tid >> 6, lane = tid & 63;
  int node = blockIdx.x * 4 + wave;
  int c4 = lane * 4;
  float4 w0 = *(const float4*)&eW[0 * HID + c4];
  float4 w1 = *(const float4*)&eW[1 * HID + c4];
  float4 w2 = *(const float4*)&eW[2 * HID + c4];
  float4 w3 = *(const float4*)&eW[3 * HID + c4];
  float4 w4 = *(const float4*)&eW[4 * HID + c4];
  float4 bi = *(const float4*)&eb[c4];
  if (node >= n) return;
  int lo = (node == 0) ? 0 : offs[node - 1];
  int hi = offs[node];
  float ax = 0.f, ay = 0.f, az = 0.f, aw = 0.f;
  if (lo < hi) {
    int2 pr = epair[lo];
    for (int p = lo; p < hi; ++p) {
      int2 nx = (p + 1 < hi) ? epair[p + 1] : pr;   // prefetch
      const float* eap = ea + (size_t)pr.x * 5;
      float e0 = eap[0], e1 = eap[1], e2 = eap[2], e3 = eap[3], e4 = eap[4];
      ushort4 hv = *(const ushort4*)&h[(size_t)pr.y * HID + c4];
      float m0 = bi.x, m1 = bi.y, m2 = bi.z, m3 = bi.w;
      m0 = fmaf(e0, w0.x, m0); m1 = fmaf(e0, w0.y, m1); m2 = fmaf(e0, w0.z, m2); m3 = fmaf(e0, w0.w, m3);
      m0 = fmaf(e1, w1.x, m0); m1 = fmaf(e1, w1.y, m1); m2 = fmaf(e1, w1.z, m2); m3 = fmaf(e1, w1.w, m3);
      m0 = fmaf(e2, w2.x, m0); m1 = fmaf(e2, w2.y, m1); m2 = fmaf(e2, w2.z, m2); m3 = fmaf(e2, w2.w, m3);
      m0 = fmaf(e3, w3.x, m0); m1 = fmaf(e3, w3.y, m1); m2 = fmaf(e3, w3.z, m2); m3 = fmaf(e3, w3.w, m3);
      m0 = fmaf(e4, w4.x, m0); m1 = fmaf(e4, w4.y, m1); m2 = fmaf(e4, w4.z, m2); m3 = fmaf(e4, w4.w, m3);
      m0 += bf2f(hv.x); m1 += bf2f(hv.y); m2 += bf2f(hv.z); m3 += bf2f(hv.w);
      ax += fmaxf(m0, 0.f); ay += fmaxf(m1, 0.f);
      az += fmaxf(m2, 0.f); aw += fmaxf(m3, 0.f);
      pr = nx;
    }
  }
  ushort4 ho = *(const ushort4*)&h[(size_t)node * HID + c4];
  ax += bf2f(ho.x); ay += bf2f(ho.y); az += bf2f(ho.z); aw += bf2f(ho.w);
  *(ushort4*)&zin[(size_t)node * HID + c4] =
      make_ushort4(f2bf(ax), f2bf(ay), f2bf(az), f2bf(aw));
}

// MFMA GEMM: out(bf16)[M,256] = A(bf16) @ Wt^T + bias; Wt is [n][k] bf16.
// Block: 32 rows x 256 cols, 4 waves (2x2), wave tile 16 rows x 128 cols.
// A-frag: lane m=lane&15 row, k=quad*8+j. B-frag: n=lane&15, k=quad*8+j.
template<int DO_RELU, int STATS>
__global__ __launch_bounds__(256) void k_gemm_mfma(const ushort_t* __restrict__ A,
    const ushort_t* __restrict__ Wt, const float* __restrict__ bias,
    ushort_t* __restrict__ out, float* __restrict__ stats, int M)
{
  __shared__ float s_sum[HID];
  __shared__ float s_sq[HID];
  int tid = threadIdx.x;
  int wave = tid >> 6, lane = tid & 63;
  int m = lane & 15, quad = lane >> 4;
  int row0 = blockIdx.x * 32 + (wave & 1) * 16;
  int col0 = (wave >> 1) * 128;
  if (STATS) { s_sum[tid] = 0.f; s_sq[tid] = 0.f; __syncthreads(); }

  int arow = row0 + m; if (arow >= M) arow = M - 1;
  const ushort_t* Ap = A + (size_t)arow * HID + quad * 8;
  const ushort_t* Wp = Wt + (size_t)(col0 + m) * HID + quad * 8;

  f32x4 acc[8];
#pragma unroll
  for (int c = 0; c < 8; ++c) acc[c] = (f32x4){0.f, 0.f, 0.f, 0.f};

#pragma unroll
  for (int kt = 0; kt < 8; ++kt) {
    bf16x8 a = *(const bf16x8*)(Ap + kt * 32);
#pragma unroll
    for (int c = 0; c < 8; ++c) {
      bf16x8 b = *(const bf16x8*)(Wp + (size_t)c * 16 * HID + kt * 32);
      acc[c] = __builtin_amdgcn_mfma_f32_16x16x32_bf16(a, b, acc[c], 0, 0, 0);
    }
  }

#pragma unroll
  for (int c = 0; c < 8; ++c) {
    int col = col0 + c * 16 + m;
    float bv = bias[col];
    float ssum = 0.f, ssq = 0.f;
#pragma unroll
    for (int reg = 0; reg < 4; ++reg) {
      int row = row0 + quad * 4 + reg;
      if (row < M) {
        float o = acc[c][reg] + bv;
        if (DO_RELU) o = fmaxf(o, 0.f);
        out[(size_t)row * HID + col] = f2bf(o);
        if (STATS) { ssum += o; ssq = fmaf(o, o, ssq); }
      }
    }
    if (STATS) {
      ssum += __shfl_xor(ssum, 16); ssum += __shfl_xor(ssum, 32);
      ssq  += __shfl_xor(ssq, 16);  ssq  += __shfl_xor(ssq, 32);
      if (quad == 0) {
        atomicAdd(&s_sum[col], ssum);
        atomicAdd(&s_sq[col], ssq);
      }
    }
  }
  if (STATS) {
    __syncthreads();
    unsafeAtomicAdd(&stats[tid], s_sum[tid]);
    unsafeAtomicAdd(&stats[HID + tid], s_sq[tid]);
  }
}

__global__ void k_bn_finalize(const float* __restrict__ stats,
    const float* __restrict__ g, const float* __restrict__ b,
    float* __restrict__ ss, int n)
{
  int j = threadIdx.x;
  float inv_n = 1.f / (float)n;
  float mu = stats[j] * inv_n;
  float var = stats[HID + j] * inv_n - mu * mu;
  float rs = rsqrtf(var + 1e-5f);
  float sc = g[j] * rs;
  ss[j] = sc;
  ss[HID + j] = b[j] - mu * sc;
}

// h(bf16) = relu(z*scale + shift) + h ; z bf16
__global__ __launch_bounds__(256) void k_bn_apply(const ushort_t* __restrict__ z,
    const float* __restrict__ ss, ushort_t* __restrict__ h, int total4)
{
  int idx = blockIdx.x * 256 + threadIdx.x;
  if (idx >= total4) return;
  int col = (idx & 63) * 4;
  ushort4 zv = *(const ushort4*)(z + (size_t)idx * 4);
  ushort4 hv = *(const ushort4*)(h + (size_t)idx * 4);
  float o0 = fmaxf(fmaf(bf2f(zv.x), ss[col + 0], ss[HID + col + 0]), 0.f) + bf2f(hv.x);
  float o1 = fmaxf(fmaf(bf2f(zv.y), ss[col + 1], ss[HID + col + 1]), 0.f) + bf2f(hv.y);
  float o2 = fmaxf(fmaf(bf2f(zv.z), ss[col + 2], ss[HID + col + 2]), 0.f) + bf2f(hv.z);
  float o3 = fmaxf(fmaf(bf2f(zv.w), ss[col + 3], ss[HID + col + 3]), 0.f) + bf2f(hv.w);
  *(ushort4*)(h + (size_t)idx * 4) = make_ushort4(f2bf(o0), f2bf(o1), f2bf(o2), f2bf(o3));
}

__device__ __forceinline__ int lbound(const int* __restrict__ b, int n, int key) {
  int lo = 0, hi = n;
  while (lo < hi) {
    int mid = (lo + hi) >> 1;
    if (b[mid] < key) lo = mid + 1; else hi = mid;
  }
  return lo;
}

// fused pool (batch sorted) + head MLP
__global__ __launch_bounds__(256) void k_head(const ushort_t* __restrict__ h,
    const int* __restrict__ batch,
    const float* __restrict__ W1, const float* __restrict__ b1,
    const float* __restrict__ W2, const float* __restrict__ b2,
    const float* __restrict__ W3, const float* __restrict__ b3,
    float* __restrict__ out)
{
  __shared__ float gf[3 * HID];
  __shared__ float g1[HID];
  __shared__ float red[4];
  int g = blockIdx.x, j = threadIdx.x;
  int lo = lbound(batch, N_NODES, g);
  int hi = lbound(batch, N_NODES, g + 1);
  float s = 0.f, mx = 0.f;  // h >= 0 by construction
  for (int i = lo; i < hi; ++i) {
    float v = bf2f(h[(size_t)i * HID + j]);
    s += v; mx = fmaxf(mx, v);
  }
  float cntv = fmaxf((float)(hi - lo), 1.f);
  gf[j] = s / cntv;
  gf[HID + j] = s;
  gf[2 * HID + j] = mx;
  __syncthreads();
  float acc = b1[j];
  for (int k = 0; k < 3 * HID; ++k) acc = fmaf(gf[k], W1[(size_t)k * HID + j], acc);
  g1[j] = fmaxf(acc, 0.f);
  __syncthreads();
  float p = 0.f;
  if (j < 128) {
    float a2 = b2[j];
    for (int k = 0; k < HID; ++k) a2 = fmaf(g1[k], W2[(size_t)k * 128 + j], a2);
    p = fmaxf(a2, 0.f) * W3[j];
  }
#pragma unroll
  for (int off = 32; off > 0; off >>= 1) p += __shfl_down(p, off);
  if ((j & 63) == 0) red[j >> 6] = p;
  __syncthreads();
  if (j == 0) out[g] = red[0] + red[1] + b3[0];
}

extern "C" void kernel_launch(void* const* d_in, const int* in_sizes, int n_in,
                              void* d_out, int out_size, void* d_ws, size_t ws_size,
                              hipStream_t stream)
{
  const float* x     = (const float*)d_in[0];
  const int*   ei    = (const int*)d_in[1];
  const float* ea    = (const float*)d_in[2];
  const int*   batch = (const int*)d_in[3];
  const float* encW  = (const float*)d_in[4];
  const float* encB  = (const float*)d_in[5];
  const float* edgeW = (const float*)d_in[6];
  const float* edgeB = (const float*)d_in[7];
  const float* W1    = (const float*)d_in[8];
  const float* b1    = (const float*)d_in[9];
  const float* W2    = (const float*)d_in[10];
  const float* b2    = (const float*)d_in[11];
  const float* bng   = (const float*)d_in[12];
  const float* bnb   = (const float*)d_in[13];
  const float* hW1   = (const float*)d_in[14];
  const float* hb1   = (const float*)d_in[15];
  const float* hW2   = (const float*)d_in[16];
  const float* hb2   = (const float*)d_in[17];
  const float* hW3   = (const float*)d_in[18];
  const float* hb3   = (const float*)d_in[19];
  float* out = (float*)d_out;

  const size_t NH = (size_t)N_NODES * HID;
  char* base = (char*)d_ws;
  auto alloc = [&](size_t bytes) -> char* {
    char* p = base; base += (bytes + 63) & ~(size_t)63; return p;
  };
  float*    stats = (float*)alloc(512 * 4);
  float*    ss    = (float*)alloc(512 * 4);
  int*      offs  = (int*)alloc(50001 * 4);
  int2*     epair = (int2*)alloc((size_t)N_EDGES * 8);
  ushort_t* Wt1   = (ushort_t*)alloc((size_t)NLAYERS * HID * HID * 2);
  ushort_t* Wt2   = (ushort_t*)alloc((size_t)NLAYERS * HID * HID * 2);
  ushort_t* zin   = (ushort_t*)alloc(NH * 2);  // also reused as z2
  ushort_t* z1    = (ushort_t*)alloc(NH * 2);
  ushort_t* h     = (ushort_t*)alloc(NH * 2);
  // total ~80.5 MB

  const int* src = ei;
  const int* dst = ei + N_EDGES;

  // CSR build + weight prep (independent of encoder)
  hipMemsetAsync(offs, 0, 50001 * sizeof(int), stream);
  k_hist<<<(N_EDGES + 255) / 256, 256, 0, stream>>>(dst, offs, N_EDGES);
  k_scan<<<1, 1024, 0, stream>>>(offs, N_NODES);
  k_fill<<<(N_EDGES + 255) / 256, 256, 0, stream>>>(src, dst, offs, epair, N_EDGES);
  k_prep<<<dim3(16, NLAYERS), 256, 0, stream>>>(W1, Wt1);
  k_prep<<<dim3(16, NLAYERS), 256, 0, stream>>>(W2, Wt2);

  k_encoder<<<(N_NODES + 7) / 8, 256, 0, stream>>>(x, encW, encB, h, N_NODES);

  const int GBLK = (N_NODES + 31) / 32;
  for (int l = 0; l < NLAYERS; ++l) {
    k_gather<<<N_NODES / 4, 256, 0, stream>>>(
        h, ea, offs, epair, edgeW + (size_t)l * 5 * HID, edgeB + (size_t)l * HID,
        zin, N_NODES);
    hipMemsetAsync(stats, 0, 512 * sizeof(float), stream);
    // z1 = relu(zin @ W1 + b1)
    k_gemm_mfma<1, 0><<<GBLK, 256, 0, stream>>>(
        zin, Wt1 + (size_t)l * HID * HID, b1 + (size_t)l * HID, z1, nullptr, N_NODES);
    // z2 = z1 @ W2 + b2 (into zin buffer), fused column stats
    k_gemm_mfma<0, 1><<<GBLK, 256, 0, stream>>>(
        z1, Wt2 + (size_t)l * HID * HID, b2 + (size_t)l * HID, zin, stats, N_NODES);
    k_bn_finalize<<<1, 256, 0, stream>>>(stats, bng + (size_t)l * HID,
                                         bnb + (size_t)l * HID, ss, N_NODES);
    k_bn_apply<<<(N_NODES * HID / 4 + 255) / 256, 256, 0, stream>>>(
        zin, ss, h, N_NODES * HID / 4);
  }

  k_head<<<G_GRAPHS, 256, 0, stream>>>(h, batch, hW1, hb1, hW2, hb2, hW3, hb3, out);
}

// Round 6
// 889.885 us; speedup vs baseline: 2.5348x; 1.3147x over previous
//
#include <hip/hip_runtime.h>

#define N_NODES 50000
#define N_EDGES 300000
#define G_GRAPHS 1024
#define HID 256
#define NLAYERS 4
#define BM 128
#define BN 128
#define LDK 36  // padded k-stride in elems (32 + 4): 72B row stride -> ~2-way LDS aliasing (free)

typedef unsigned short ushort_t;
typedef __attribute__((ext_vector_type(8))) short bf16x8;
typedef __attribute__((ext_vector_type(8))) unsigned short u16x8;
typedef __attribute__((ext_vector_type(4))) float f32x4;

__device__ __forceinline__ float bf2f(ushort_t u) {
  unsigned int x = ((unsigned int)u) << 16;
  return __builtin_bit_cast(float, x);
}
__device__ __forceinline__ ushort_t f2bf(float f) {
  unsigned int x = __builtin_bit_cast(unsigned int, f);
  unsigned int lsb = (x >> 16) & 1u;
  x += 0x7fffu + lsb;
  return (ushort_t)(x >> 16);
}

// h(bf16) = relu(x @ encW + encB)
__global__ __launch_bounds__(256) void k_encoder(const float* __restrict__ x,
    const float* __restrict__ W, const float* __restrict__ b,
    ushort_t* __restrict__ h, int n)
{
  int j = threadIdx.x;
  float wcol[11];
#pragma unroll
  for (int k = 0; k < 11; ++k) wcol[k] = W[k * HID + j];
  float bj = b[j];
  __shared__ float xs[8][11];
  int base = blockIdx.x * 8;
  if (j < 88) {
    int r = j / 11, k = j % 11;
    int row = base + r;
    if (row < n) xs[r][k] = x[row * 11 + k];
  }
  __syncthreads();
#pragma unroll
  for (int r = 0; r < 8; ++r) {
    int row = base + r;
    if (row >= n) break;
    float acc = bj;
#pragma unroll
    for (int k = 0; k < 11; ++k) acc += xs[r][k] * wcol[k];
    h[(size_t)row * HID + j] = f2bf(fmaxf(acc, 0.f));
  }
}

// ---- CSR build ----
__global__ __launch_bounds__(256) void k_hist(const int* __restrict__ dst,
    int* __restrict__ offs, int E)
{
  int e = blockIdx.x * 256 + threadIdx.x;
  if (e < E) atomicAdd(&offs[dst[e]], 1);
}

__global__ __launch_bounds__(1024) void k_scan(int* __restrict__ offs, int n)
{
  __shared__ int wsum[16];
  __shared__ int s_carry;
  int tid = threadIdx.x, lane = tid & 63, wid = tid >> 6;
  if (tid == 0) s_carry = 0;
  __syncthreads();
  for (int base = 0; base < n; base += 1024) {
    int idx = base + tid;
    int v = (idx < n) ? offs[idx] : 0;
    int x = v;
#pragma unroll
    for (int off = 1; off < 64; off <<= 1) {
      int t = __shfl_up(x, off);
      if (lane >= off) x += t;
    }
    if (lane == 63) wsum[wid] = x;
    __syncthreads();
    if (wid == 0 && lane < 16) {
      int w = wsum[lane];
#pragma unroll
      for (int off = 1; off < 16; off <<= 1) {
        int t = __shfl_up(w, off);
        if (lane >= off) w += t;
      }
      wsum[lane] = w;
    }
    __syncthreads();
    int wbase = (wid == 0) ? 0 : wsum[wid - 1];
    int excl = s_carry + wbase + x - v;
    int total = wsum[15];
    __syncthreads();
    if (idx < n) offs[idx] = excl;
    if (tid == 0) s_carry += total;
    __syncthreads();
  }
  if (tid == 0) offs[n] = s_carry;
}

__global__ __launch_bounds__(256) void k_fill(const int* __restrict__ src,
    const int* __restrict__ dst, int* __restrict__ offs,
    int2* __restrict__ epair, int E)
{
  int e = blockIdx.x * 256 + threadIdx.x;
  if (e < E) {
    int d = dst[e];
    int p = atomicAdd(&offs[d], 1);
    epair[p] = make_int2(e, src[e]);
  }
}

// W [256][256] f32 -> Wt [n][k] bf16 (transposed), nmats via grid.y
__global__ __launch_bounds__(256) void k_prep(const float* __restrict__ W,
    ushort_t* __restrict__ Wt)
{
  __shared__ float ld[16][257];
  int mat = blockIdx.y;
  int k0 = blockIdx.x * 16;
  const float* Wm = W + (size_t)mat * HID * HID;
  ushort_t* Wtm = Wt + (size_t)mat * HID * HID;
  int tid = threadIdx.x;
#pragma unroll
  for (int i = 0; i < 16; ++i) ld[i][tid] = Wm[(size_t)(k0 + i) * HID + tid];
  __syncthreads();
#pragma unroll
  for (int v = 0; v < 4; ++v) {
    ushort4 u = make_ushort4(f2bf(ld[v*4+0][tid]), f2bf(ld[v*4+1][tid]),
                             f2bf(ld[v*4+2][tid]), f2bf(ld[v*4+3][tid]));
    *(ushort4*)&Wtm[(size_t)tid * HID + k0 + v * 4] = u;
  }
}

// one wave per node: zin[i] = h[i] + sum_in-edges relu(h[src] + ea@eW + eb)
__global__ __launch_bounds__(256) void k_gather(const ushort_t* __restrict__ h,
    const float* __restrict__ ea, const int* __restrict__ offs,
    const int2* __restrict__ epair, const float* __restrict__ eW,
    const float* __restrict__ eb, ushort_t* __restrict__ zin, int n)
{
  int tid = threadIdx.x;
  int wave = tid >> 6, lane = tid & 63;
  int node = blockIdx.x * 4 + wave;
  int c4 = lane * 4;
  float4 w0 = *(const float4*)&eW[0 * HID + c4];
  float4 w1 = *(const float4*)&eW[1 * HID + c4];
  float4 w2 = *(const float4*)&eW[2 * HID + c4];
  float4 w3 = *(const float4*)&eW[3 * HID + c4];
  float4 w4 = *(const float4*)&eW[4 * HID + c4];
  float4 bi = *(const float4*)&eb[c4];
  if (node >= n) return;
  int lo = (node == 0) ? 0 : offs[node - 1];
  int hi = offs[node];
  float ax = 0.f, ay = 0.f, az = 0.f, aw = 0.f;
  if (lo < hi) {
    int2 pr = epair[lo];
    for (int p = lo; p < hi; ++p) {
      int2 nx = (p + 1 < hi) ? epair[p + 1] : pr;   // prefetch
      const float* eap = ea + (size_t)pr.x * 5;
      float e0 = eap[0], e1 = eap[1], e2 = eap[2], e3 = eap[3], e4 = eap[4];
      ushort4 hv = *(const ushort4*)&h[(size_t)pr.y * HID + c4];
      float m0 = bi.x, m1 = bi.y, m2 = bi.z, m3 = bi.w;
      m0 = fmaf(e0, w0.x, m0); m1 = fmaf(e0, w0.y, m1); m2 = fmaf(e0, w0.z, m2); m3 = fmaf(e0, w0.w, m3);
      m0 = fmaf(e1, w1.x, m0); m1 = fmaf(e1, w1.y, m1); m2 = fmaf(e1, w1.z, m2); m3 = fmaf(e1, w1.w, m3);
      m0 = fmaf(e2, w2.x, m0); m1 = fmaf(e2, w2.y, m1); m2 = fmaf(e2, w2.z, m2); m3 = fmaf(e2, w2.w, m3);
      m0 = fmaf(e3, w3.x, m0); m1 = fmaf(e3, w3.y, m1); m2 = fmaf(e3, w3.z, m2); m3 = fmaf(e3, w3.w, m3);
      m0 = fmaf(e4, w4.x, m0); m1 = fmaf(e4, w4.y, m1); m2 = fmaf(e4, w4.z, m2); m3 = fmaf(e4, w4.w, m3);
      m0 += bf2f(hv.x); m1 += bf2f(hv.y); m2 += bf2f(hv.z); m3 += bf2f(hv.w);
      ax += fmaxf(m0, 0.f); ay += fmaxf(m1, 0.f);
      az += fmaxf(m2, 0.f); aw += fmaxf(m3, 0.f);
      pr = nx;
    }
  }
  ushort4 ho = *(const ushort4*)&h[(size_t)node * HID + c4];
  ax += bf2f(ho.x); ay += bf2f(ho.y); az += bf2f(ho.z); aw += bf2f(ho.w);
  *(ushort4*)&zin[(size_t)node * HID + c4] =
      make_ushort4(f2bf(ax), f2bf(ay), f2bf(az), f2bf(aw));
}

// LDS-staged MFMA GEMM: out(bf16)[M,256] = A(bf16)[M,256] @ Wt^T + bias.
// Wt is [n][k] bf16. Block: 128x128 tile, 4 waves 2x2, wave tile 64x64,
// BK=32 (one 16x16x32 MFMA per k-step per acc tile).
template<int DO_RELU, int STATS>
__global__ __launch_bounds__(256) void k_gemm_mfma(const ushort_t* __restrict__ A,
    const ushort_t* __restrict__ Wt, const float* __restrict__ bias,
    ushort_t* __restrict__ out, float* __restrict__ stats, int M)
{
  __shared__ ushort_t As[BM * LDK];
  __shared__ ushort_t Ws[BN * LDK];
  __shared__ float s_sum[BN];
  __shared__ float s_sq[BN];
  int tid = threadIdx.x;
  int wave = tid >> 6, lane = tid & 63;
  int m = lane & 15, quad = lane >> 4;
  int wm = wave & 1, wn = wave >> 1;
  int row0 = blockIdx.x * BM;
  int col0 = blockIdx.y * BN;
  if (STATS && tid < BN) { s_sum[tid] = 0.f; s_sq[tid] = 0.f; }

  int sr = tid >> 2;            // staging row within 64-row half
  int sq = (tid & 3) * 8;       // k-elem offset (8 elems = 16B)

  f32x4 acc[4][4];
#pragma unroll
  for (int mt = 0; mt < 4; ++mt)
#pragma unroll
    for (int nt = 0; nt < 4; ++nt) acc[mt][nt] = (f32x4){0.f, 0.f, 0.f, 0.f};

#pragma unroll
  for (int kt = 0; kt < 8; ++kt) {
    int k0 = kt * 32;
    u16x8 av0 = {}, av1 = {};
    int gr0 = row0 + sr, gr1 = row0 + 64 + sr;
    if (gr0 < M) av0 = *(const u16x8*)(A + (size_t)gr0 * HID + k0 + sq);
    if (gr1 < M) av1 = *(const u16x8*)(A + (size_t)gr1 * HID + k0 + sq);
    u16x8 wv0 = *(const u16x8*)(Wt + (size_t)(col0 + sr) * HID + k0 + sq);
    u16x8 wv1 = *(const u16x8*)(Wt + (size_t)(col0 + 64 + sr) * HID + k0 + sq);
    __syncthreads();  // previous iteration's compute done before overwrite
    *(u16x8*)&As[sr * LDK + sq] = av0;
    *(u16x8*)&As[(64 + sr) * LDK + sq] = av1;
    *(u16x8*)&Ws[sr * LDK + sq] = wv0;
    *(u16x8*)&Ws[(64 + sr) * LDK + sq] = wv1;
    __syncthreads();
    bf16x8 af[4], bfr[4];
#pragma unroll
    for (int mt = 0; mt < 4; ++mt)
      af[mt] = *(const bf16x8*)&As[(wm * 64 + mt * 16 + m) * LDK + quad * 8];
#pragma unroll
    for (int nt = 0; nt < 4; ++nt)
      bfr[nt] = *(const bf16x8*)&Ws[(wn * 64 + nt * 16 + m) * LDK + quad * 8];
#pragma unroll
    for (int mt = 0; mt < 4; ++mt)
#pragma unroll
      for (int nt = 0; nt < 4; ++nt)
        acc[mt][nt] = __builtin_amdgcn_mfma_f32_16x16x32_bf16(
            af[mt], bfr[nt], acc[mt][nt], 0, 0, 0);
  }

  // epilogue: C/D layout col=lane&15 (n), row=quad*4+reg
#pragma unroll
  for (int nt = 0; nt < 4; ++nt) {
    int col = col0 + wn * 64 + nt * 16 + m;
    float bv = bias[col];
    float ssum = 0.f, ssq = 0.f;
#pragma unroll
    for (int mt = 0; mt < 4; ++mt) {
#pragma unroll
      for (int reg = 0; reg < 4; ++reg) {
        int row = row0 + wm * 64 + mt * 16 + quad * 4 + reg;
        if (row < M) {
          float o = acc[mt][nt][reg] + bv;
          if (DO_RELU) o = fmaxf(o, 0.f);
          out[(size_t)row * HID + col] = f2bf(o);
          if (STATS) { ssum += o; ssq = fmaf(o, o, ssq); }
        }
      }
    }
    if (STATS) {
      ssum += __shfl_xor(ssum, 16); ssum += __shfl_xor(ssum, 32);
      ssq  += __shfl_xor(ssq, 16);  ssq  += __shfl_xor(ssq, 32);
      if (quad == 0) {
        atomicAdd(&s_sum[wn * 64 + nt * 16 + m], ssum);
        atomicAdd(&s_sq[wn * 64 + nt * 16 + m], ssq);
      }
    }
  }
  if (STATS) {
    __syncthreads();
    if (tid < BN) {
      unsafeAtomicAdd(&stats[col0 + tid], s_sum[tid]);
      unsafeAtomicAdd(&stats[HID + col0 + tid], s_sq[tid]);
    }
  }
}

__global__ void k_bn_finalize(const float* __restrict__ stats,
    const float* __restrict__ g, const float* __restrict__ b,
    float* __restrict__ ss, int n)
{
  int j = threadIdx.x;
  float inv_n = 1.f / (float)n;
  float mu = stats[j] * inv_n;
  float var = stats[HID + j] * inv_n - mu * mu;
  float rs = rsqrtf(var + 1e-5f);
  float sc = g[j] * rs;
  ss[j] = sc;
  ss[HID + j] = b[j] - mu * sc;
}

// h(bf16) = relu(z*scale + shift) + h ; z bf16
__global__ __launch_bounds__(256) void k_bn_apply(const ushort_t* __restrict__ z,
    const float* __restrict__ ss, ushort_t* __restrict__ h, int total4)
{
  int idx = blockIdx.x * 256 + threadIdx.x;
  if (idx >= total4) return;
  int col = (idx & 63) * 4;
  ushort4 zv = *(const ushort4*)(z + (size_t)idx * 4);
  ushort4 hv = *(const ushort4*)(h + (size_t)idx * 4);
  float o0 = fmaxf(fmaf(bf2f(zv.x), ss[col + 0], ss[HID + col + 0]), 0.f) + bf2f(hv.x);
  float o1 = fmaxf(fmaf(bf2f(zv.y), ss[col + 1], ss[HID + col + 1]), 0.f) + bf2f(hv.y);
  float o2 = fmaxf(fmaf(bf2f(zv.z), ss[col + 2], ss[HID + col + 2]), 0.f) + bf2f(hv.z);
  float o3 = fmaxf(fmaf(bf2f(zv.w), ss[col + 3], ss[HID + col + 3]), 0.f) + bf2f(hv.w);
  *(ushort4*)(h + (size_t)idx * 4) = make_ushort4(f2bf(o0), f2bf(o1), f2bf(o2), f2bf(o3));
}

__device__ __forceinline__ int lbound(const int* __restrict__ b, int n, int key) {
  int lo = 0, hi = n;
  while (lo < hi) {
    int mid = (lo + hi) >> 1;
    if (b[mid] < key) lo = mid + 1; else hi = mid;
  }
  return lo;
}

// fused pool (batch sorted) + head MLP
__global__ __launch_bounds__(256) void k_head(const ushort_t* __restrict__ h,
    const int* __restrict__ batch,
    const float* __restrict__ W1, const float* __restrict__ b1,
    const float* __restrict__ W2, const float* __restrict__ b2,
    const float* __restrict__ W3, const float* __restrict__ b3,
    float* __restrict__ out)
{
  __shared__ float gf[3 * HID];
  __shared__ float g1[HID];
  __shared__ float red[4];
  int g = blockIdx.x, j = threadIdx.x;
  int lo = lbound(batch, N_NODES, g);
  int hi = lbound(batch, N_NODES, g + 1);
  float s = 0.f, mx = 0.f;  // h >= 0 by construction
  for (int i = lo; i < hi; ++i) {
    float v = bf2f(h[(size_t)i * HID + j]);
    s += v; mx = fmaxf(mx, v);
  }
  float cntv = fmaxf((float)(hi - lo), 1.f);
  gf[j] = s / cntv;
  gf[HID + j] = s;
  gf[2 * HID + j] = mx;
  __syncthreads();
  float acc = b1[j];
  for (int k = 0; k < 3 * HID; ++k) acc = fmaf(gf[k], W1[(size_t)k * HID + j], acc);
  g1[j] = fmaxf(acc, 0.f);
  __syncthreads();
  float p = 0.f;
  if (j < 128) {
    float a2 = b2[j];
    for (int k = 0; k < HID; ++k) a2 = fmaf(g1[k], W2[(size_t)k * 128 + j], a2);
    p = fmaxf(a2, 0.f) * W3[j];
  }
#pragma unroll
  for (int off = 32; off > 0; off >>= 1) p += __shfl_down(p, off);
  if ((j & 63) == 0) red[j >> 6] = p;
  __syncthreads();
  if (j == 0) out[g] = red[0] + red[1] + b3[0];
}

extern "C" void kernel_launch(void* const* d_in, const int* in_sizes, int n_in,
                              void* d_out, int out_size, void* d_ws, size_t ws_size,
                              hipStream_t stream)
{
  const float* x     = (const float*)d_in[0];
  const int*   ei    = (const int*)d_in[1];
  const float* ea    = (const float*)d_in[2];
  const int*   batch = (const int*)d_in[3];
  const float* encW  = (const float*)d_in[4];
  const float* encB  = (const float*)d_in[5];
  const float* edgeW = (const float*)d_in[6];
  const float* edgeB = (const float*)d_in[7];
  const float* W1    = (const float*)d_in[8];
  const float* b1    = (const float*)d_in[9];
  const float* W2    = (const float*)d_in[10];
  const float* b2    = (const float*)d_in[11];
  const float* bng   = (const float*)d_in[12];
  const float* bnb   = (const float*)d_in[13];
  const float* hW1   = (const float*)d_in[14];
  const float* hb1   = (const float*)d_in[15];
  const float* hW2   = (const float*)d_in[16];
  const float* hb2   = (const float*)d_in[17];
  const float* hW3   = (const float*)d_in[18];
  const float* hb3   = (const float*)d_in[19];
  float* out = (float*)d_out;

  const size_t NH = (size_t)N_NODES * HID;
  char* base = (char*)d_ws;
  auto alloc = [&](size_t bytes) -> char* {
    char* p = base; base += (bytes + 63) & ~(size_t)63; return p;
  };
  float*    stats = (float*)alloc(512 * 4);
  float*    ss    = (float*)alloc(512 * 4);
  int*      offs  = (int*)alloc(50001 * 4);
  int2*     epair = (int2*)alloc((size_t)N_EDGES * 8);
  ushort_t* Wt1   = (ushort_t*)alloc((size_t)NLAYERS * HID * HID * 2);
  ushort_t* Wt2   = (ushort_t*)alloc((size_t)NLAYERS * HID * HID * 2);
  ushort_t* zin   = (ushort_t*)alloc(NH * 2);  // also reused as z2
  ushort_t* z1    = (ushort_t*)alloc(NH * 2);
  ushort_t* h     = (ushort_t*)alloc(NH * 2);
  // total ~80.5 MB

  const int* src = ei;
  const int* dst = ei + N_EDGES;

  // CSR build + weight prep (independent of encoder)
  hipMemsetAsync(offs, 0, 50001 * sizeof(int), stream);
  k_hist<<<(N_EDGES + 255) / 256, 256, 0, stream>>>(dst, offs, N_EDGES);
  k_scan<<<1, 1024, 0, stream>>>(offs, N_NODES);
  k_fill<<<(N_EDGES + 255) / 256, 256, 0, stream>>>(src, dst, offs, epair, N_EDGES);
  k_prep<<<dim3(16, NLAYERS), 256, 0, stream>>>(W1, Wt1);
  k_prep<<<dim3(16, NLAYERS), 256, 0, stream>>>(W2, Wt2);

  k_encoder<<<(N_NODES + 7) / 8, 256, 0, stream>>>(x, encW, encB, h, N_NODES);

  const dim3 GGRID((N_NODES + BM - 1) / BM, HID / BN);
  for (int l = 0; l < NLAYERS; ++l) {
    k_gather<<<N_NODES / 4, 256, 0, stream>>>(
        h, ea, offs, epair, edgeW + (size_t)l * 5 * HID, edgeB + (size_t)l * HID,
        zin, N_NODES);
    hipMemsetAsync(stats, 0, 512 * sizeof(float), stream);
    // z1 = relu(zin @ W1 + b1)
    k_gemm_mfma<1, 0><<<GGRID, 256, 0, stream>>>(
        zin, Wt1 + (size_t)l * HID * HID, b1 + (size_t)l * HID, z1, nullptr, N_NODES);
    // z2 = z1 @ W2 + b2 (into zin buffer), fused column stats
    k_gemm_mfma<0, 1><<<GGRID, 256, 0, stream>>>(
        z1, Wt2 + (size_t)l * HID * HID, b2 + (size_t)l * HID, zin, stats, N_NODES);
    k_bn_finalize<<<1, 256, 0, stream>>>(stats, bng + (size_t)l * HID,
                                         bnb + (size_t)l * HID, ss, N_NODES);
    k_bn_apply<<<(N_NODES * HID / 4 + 255) / 256, 256, 0, stream>>>(
        zin, ss, h, N_NODES * HID / 4);
  }

  k_head<<<G_GRAPHS, 256, 0, stream>>>(h, batch, hW1, hb1, hW2, hb2, hW3, hb3, out);
}